// Round 1
// baseline (975.348 us; speedup 1.0000x reference)
//
#include <hip/hip_runtime.h>

#define H  64
#define G4 256   // 4*H

// fast sigmoid/tanh: v_exp_f32 + v_rcp_f32. Safe at +-inf:
//   x->-inf: exp(-x)=inf -> rcp(inf)=0 ; x->+inf: exp(-x)=0 -> rcp(1)=1
__device__ __forceinline__ float sigm(float x) {
    return __builtin_amdgcn_rcpf(1.0f + __expf(-x));
}
__device__ __forceinline__ float tanh_s(float x) {
    return fmaf(2.0f, sigm(2.0f * x), -1.0f);
}

__device__ __forceinline__ float bcast(float v, int lane) {
    return __int_as_float(__builtin_amdgcn_readlane(__float_as_int(v), lane));
}

// P[v][g] = sum_h table[v][h] * w_ih[g][h] + b_ih[g] + b_hh[g], table[0] = 0
__global__ __launch_bounds__(256)
void proj_kernel(const float* __restrict__ emb,
                 const float* __restrict__ w_ih,
                 const float* __restrict__ b_ih,
                 const float* __restrict__ b_hh,
                 float* __restrict__ P,
                 int V)
{
    const int j  = threadIdx.x;       // output gate index 0..255
    const int v0 = blockIdx.x * 8;

    __shared__ float es[8][H];
    // cooperative load of 8 embedding rows (512 floats, 2 per thread)
    {
        int idx = j;
        #pragma unroll
        for (int rep = 0; rep < 2; ++rep, idx += 256) {
            int r = idx >> 6, col = idx & 63;
            int v = v0 + r;
            float val = 0.0f;
            if (v < V && v != 0) val = emb[v * H + col];   // padding_idx=0
            es[r][col] = val;
        }
    }

    float w[H];
    const float4* w4 = reinterpret_cast<const float4*>(w_ih + j * H);
    #pragma unroll
    for (int i = 0; i < 16; ++i) {
        float4 t = w4[i];
        w[4*i] = t.x; w[4*i+1] = t.y; w[4*i+2] = t.z; w[4*i+3] = t.w;
    }
    float bias = b_ih[j] + b_hh[j];
    __syncthreads();

    #pragma unroll
    for (int r = 0; r < 8; ++r) {
        int v = v0 + r;
        if (v >= V) break;
        float a0 = 0, a1 = 0, a2 = 0, a3 = 0;
        #pragma unroll
        for (int k = 0; k < H; k += 4) {
            a0 = fmaf(es[r][k+0], w[k+0], a0);
            a1 = fmaf(es[r][k+1], w[k+1], a1);
            a2 = fmaf(es[r][k+2], w[k+2], a2);
            a3 = fmaf(es[r][k+3], w[k+3], a3);
        }
        P[v * G4 + j] = bias + ((a0 + a1) + (a2 + a3));
    }
}

// One block per batch element. 4 waves; wave w owns gate w (rows 64w..64w+63
// of w_hh, in VGPRs). Every wave redundantly keeps full h,c (one elem/lane),
// so the h broadcast in the matvec is v_readlane within the own wave.
// Only the gate exchange crosses waves: double-buffered LDS + 1 barrier/step.
__global__ __launch_bounds__(256, 1)
void lstm_kernel(const int* __restrict__ x,      // [B,T]
                 const float* __restrict__ Pf,   // [V,4H]
                 const float* __restrict__ Pb,   // [V,4H]
                 const float* __restrict__ w_hh, // [4H,H] (forward)
                 const float* __restrict__ w_fc, // [12,2H]
                 const float* __restrict__ b_fc, // [12]
                 float* __restrict__ out,        // [B,12]
                 int T)
{
    const int b    = blockIdx.x;
    const int j    = threadIdx.x;   // gate-output row 0..255
    const int lane = j & 63;
    const int gate = j >> 6;        // == wave id: 0=i 1=f 2=g 3=o

    // per-thread recurrent weight row
    float w[H];
    const float4* w4 = reinterpret_cast<const float4*>(w_hh + j * H);
    #pragma unroll
    for (int i = 0; i < 16; ++i) {
        float4 t = w4[i];
        w[4*i] = t.x; w[4*i+1] = t.y; w[4*i+2] = t.z; w[4*i+3] = t.w;
    }

    // branchless activation: act = Aa * sigm(ms*s) + Ba
    const float ms = (gate == 2) ? 2.0f : 1.0f;
    const float Aa = (gate == 2) ? 2.0f : 1.0f;
    const float Ba = (gate == 2) ? -1.0f : 0.0f;

    __shared__ float g_s[2][G4];
    __shared__ float hf_s[H];
    __shared__ float hb_s[H];

    const int* __restrict__ xrow = x + (long)b * T;

    float h = 0.0f;   // lane's h value (replicated across all 4 waves)
    float c = 0.0f;

    int   tok_next = (T > 1) ? xrow[1] : 0;
    float p_cur    = Pf[xrow[0] * G4 + j];

    for (int t = 0; t < T; ++t) {
        // prefetch next timestep's projected input (L2-resident gather)
        float p_next = 0.0f;
        if (t + 1 < T) p_next = Pf[tok_next * G4 + j];
        int tok_next2 = (t + 2 < T) ? xrow[t + 2] : 0;

        // s = p_cur + sum_k w[k] * h[k]   (h broadcast via readlane)
        float a0 = 0, a1 = 0, a2 = 0, a3 = 0;
        #pragma unroll
        for (int k = 0; k < H; k += 4) {
            float h0 = bcast(h, k+0);
            float h1 = bcast(h, k+1);
            float h2 = bcast(h, k+2);
            float h3 = bcast(h, k+3);
            a0 = fmaf(w[k+0], h0, a0);
            a1 = fmaf(w[k+1], h1, a1);
            a2 = fmaf(w[k+2], h2, a2);
            a3 = fmaf(w[k+3], h3, a3);
        }
        float s   = p_cur + ((a0 + a1) + (a2 + a3));
        float act = fmaf(Aa, sigm(ms * s), Ba);

        const int ph = t & 1;
        g_s[ph][j] = act;
        __syncthreads();   // the single per-step barrier (gate exchange)

        float gi = g_s[ph][lane];
        float gf = g_s[ph][H   + lane];
        float gg = g_s[ph][2*H + lane];
        float go = g_s[ph][3*H + lane];
        c = fmaf(gf, c, gi * gg);
        h = go * tanh_s(c);

        p_cur    = p_next;
        tok_next = tok_next2;
    }

    __syncthreads();   // protect g_s[0] reuse below

    // backward LSTM: exactly one step (hs_b[0]) with zero initial state
    {
        int   tokL = xrow[T - 1];
        float gb   = Pb[tokL * G4 + j];
        g_s[0][j]  = fmaf(Aa, sigm(ms * gb), Ba);
    }
    if (gate == 0) hf_s[lane] = h;
    __syncthreads();

    if (j < H) {
        float i_ = g_s[0][j];
        float gg = g_s[0][2*H + j];
        float go = g_s[0][3*H + j];
        float cb = i_ * gg;               // f*c0 = 0
        hb_s[j] = go * tanh_s(cb);
    }
    __syncthreads();

    // final FC: y[b, j] = b_fc[j] + [h_f | h_b] . w_fc[j]
    if (j < 12) {
        float acc = b_fc[j];
        const float* wf = w_fc + j * (2 * H);
        #pragma unroll
        for (int k = 0; k < H; ++k) acc = fmaf(hf_s[k], wf[k], acc);
        #pragma unroll
        for (int k = 0; k < H; ++k) acc = fmaf(hb_s[k], wf[H + k], acc);
        out[b * 12 + j] = acc;
    }
}

extern "C" void kernel_launch(void* const* d_in, const int* in_sizes, int n_in,
                              void* d_out, int out_size, void* d_ws, size_t ws_size,
                              hipStream_t stream)
{
    const int*   x      = (const int*)  d_in[0];
    const float* emb    = (const float*)d_in[1];
    const float* w_ih_f = (const float*)d_in[2];
    const float* w_hh_f = (const float*)d_in[3];
    const float* b_ih_f = (const float*)d_in[4];
    const float* b_hh_f = (const float*)d_in[5];
    const float* w_ih_b = (const float*)d_in[6];
    // d_in[7] = w_hh_b (unused: backward runs exactly one step from zero state)
    const float* b_ih_b = (const float*)d_in[8];
    const float* b_hh_b = (const float*)d_in[9];
    const float* w_fc   = (const float*)d_in[10];
    const float* b_fc   = (const float*)d_in[11];
    float* out = (float*)d_out;

    const int B = out_size / 12;
    const int T = in_sizes[0] / B;
    const int V = in_sizes[1] / H;

    float* Pf = (float*)d_ws;                   // [V,4H]
    float* Pb = Pf + (size_t)V * G4;            // [V,4H]  (4 MB total)

    int pblocks = (V + 7) / 8;
    proj_kernel<<<pblocks, 256, 0, stream>>>(emb, w_ih_f, b_ih_f, b_hh_f, Pf, V);
    proj_kernel<<<pblocks, 256, 0, stream>>>(emb, w_ih_b, b_ih_b, b_hh_b, Pb, V);
    lstm_kernel<<<B, 256, 0, stream>>>(x, Pf, Pb, w_hh_f, w_fc, b_fc, out, T);
}

// Round 2
// 971.213 us; speedup vs baseline: 1.0043x; 1.0043x over previous
//
#include <hip/hip_runtime.h>

#define H  64
#define G4 256   // 4*H

// fast sigmoid/tanh: v_exp_f32 + v_rcp_f32. Safe at +-inf:
//   x->-inf: exp(-x)=inf -> rcp(inf)=0 ; x->+inf: exp(-x)=0 -> rcp(1)=1
__device__ __forceinline__ float sigm(float x) {
    return __builtin_amdgcn_rcpf(1.0f + __expf(-x));
}
__device__ __forceinline__ float tanh_s(float x) {
    return fmaf(2.0f, sigm(2.0f * x), -1.0f);
}

__device__ __forceinline__ float bcast(float v, int lane) {
    return __int_as_float(__builtin_amdgcn_readlane(__float_as_int(v), lane));
}

// P[v][g] = sum_h table[v][h] * w_ih[g][h] + b_ih[g] + b_hh[g], table[0] = 0
// blockIdx.y = 0 -> forward params, 1 -> backward params.
__global__ __launch_bounds__(256)
void proj_kernel(const float* __restrict__ emb,
                 const float* __restrict__ w_ih_f,
                 const float* __restrict__ b_ih_f,
                 const float* __restrict__ b_hh_f,
                 const float* __restrict__ w_ih_b,
                 const float* __restrict__ b_ih_b,
                 const float* __restrict__ b_hh_b,
                 float* __restrict__ Pf,
                 float* __restrict__ Pb,
                 int V)
{
    const int j  = threadIdx.x;       // output gate index 0..255
    const int v0 = blockIdx.x * 8;
    const bool bwd = (blockIdx.y != 0);

    const float* __restrict__ w_ih = bwd ? w_ih_b : w_ih_f;
    const float* __restrict__ b_ih = bwd ? b_ih_b : b_ih_f;
    const float* __restrict__ b_hh = bwd ? b_hh_b : b_hh_f;
    float* __restrict__ P          = bwd ? Pb     : Pf;

    __shared__ float es[8][H];
    // cooperative load of 8 embedding rows (512 floats, 2 per thread)
    {
        int idx = j;
        #pragma unroll
        for (int rep = 0; rep < 2; ++rep, idx += 256) {
            int r = idx >> 6, col = idx & 63;
            int v = v0 + r;
            float val = 0.0f;
            if (v < V && v != 0) val = emb[v * H + col];   // padding_idx=0
            es[r][col] = val;
        }
    }

    float w[H];
    const float4* w4 = reinterpret_cast<const float4*>(w_ih + j * H);
    #pragma unroll
    for (int i = 0; i < 16; ++i) {
        float4 t = w4[i];
        w[4*i] = t.x; w[4*i+1] = t.y; w[4*i+2] = t.z; w[4*i+3] = t.w;
    }
    // pin w[] into VGPRs (prevents rematerialized reloads)
    #pragma unroll
    for (int i = 0; i < H; ++i) asm volatile("" : "+v"(w[i]));

    float bias = b_ih[j] + b_hh[j];
    __syncthreads();

    #pragma unroll
    for (int r = 0; r < 8; ++r) {
        int v = v0 + r;
        if (v >= V) break;
        float a0 = 0, a1 = 0, a2 = 0, a3 = 0;
        #pragma unroll
        for (int k = 0; k < H; k += 4) {
            a0 = fmaf(es[r][k+0], w[k+0], a0);
            a1 = fmaf(es[r][k+1], w[k+1], a1);
            a2 = fmaf(es[r][k+2], w[k+2], a2);
            a3 = fmaf(es[r][k+3], w[k+3], a3);
        }
        P[v * G4 + j] = bias + ((a0 + a1) + (a2 + a3));
    }
}

// One block per batch element. 4 waves; wave w owns gate w (rows 64w..64w+63
// of w_hh, in VGPRs). Every wave redundantly keeps full h,c (one elem/lane),
// so the h broadcast in the matvec is v_readlane within the own wave.
// Only the gate exchange crosses waves: double-buffered LDS + 1 barrier/step.
__global__ __launch_bounds__(256, 1)
void lstm_kernel(const int* __restrict__ x,      // [B,T]
                 const float* __restrict__ Pf,   // [V,4H]
                 const float* __restrict__ Pb,   // [V,4H]
                 const float* __restrict__ w_hh, // [4H,H] (forward)
                 const float* __restrict__ w_fc, // [12,2H]
                 const float* __restrict__ b_fc, // [12]
                 float* __restrict__ out,        // [B,12]
                 int T)
{
    const int b    = blockIdx.x;
    const int j    = threadIdx.x;   // gate-output row 0..255
    const int lane = j & 63;
    const int gate = j >> 6;        // == wave id: 0=i 1=f 2=g 3=o

    // per-thread recurrent weight row
    float w[H];
    const float4* w4 = reinterpret_cast<const float4*>(w_hh + j * H);
    #pragma unroll
    for (int i = 0; i < 16; ++i) {
        float4 t = w4[i];
        w[4*i] = t.x; w[4*i+1] = t.y; w[4*i+2] = t.z; w[4*i+3] = t.w;
    }
    // pin w[] into VGPRs: the compiler otherwise rematerializes these 16
    // global_load_dwordx4 EVERY timestep (R1 evidence: VGPR_Count=40,
    // ~1100 cyc/step = 64KB/step L1 reload). asm makes the values opaque.
    #pragma unroll
    for (int i = 0; i < H; ++i) asm volatile("" : "+v"(w[i]));

    // branchless activation: act = Aa * sigm(ms*s) + Ba
    const float ms = (gate == 2) ? 2.0f : 1.0f;
    const float Aa = (gate == 2) ? 2.0f : 1.0f;
    const float Ba = (gate == 2) ? -1.0f : 0.0f;

    __shared__ float g_s[2][G4];
    __shared__ float hf_s[H];
    __shared__ float hb_s[H];

    const int* __restrict__ xrow = x + (long)b * T;

    float h = 0.0f;   // lane's h value (replicated across all 4 waves)
    float c = 0.0f;

    int   tok_next = (T > 1) ? xrow[1] : 0;
    float p_cur    = Pf[xrow[0] * G4 + j];

    for (int t = 0; t < T; ++t) {
        // prefetch next timestep's projected input (L2-resident gather)
        float p_next = 0.0f;
        if (t + 1 < T) p_next = Pf[tok_next * G4 + j];
        int tok_next2 = (t + 2 < T) ? xrow[t + 2] : 0;

        // s = p_cur + sum_k w[k] * h[k]   (h broadcast via readlane)
        float a0 = 0, a1 = 0, a2 = 0, a3 = 0;
        #pragma unroll
        for (int k = 0; k < H; k += 4) {
            float h0 = bcast(h, k+0);
            float h1 = bcast(h, k+1);
            float h2 = bcast(h, k+2);
            float h3 = bcast(h, k+3);
            a0 = fmaf(w[k+0], h0, a0);
            a1 = fmaf(w[k+1], h1, a1);
            a2 = fmaf(w[k+2], h2, a2);
            a3 = fmaf(w[k+3], h3, a3);
        }
        float s   = p_cur + ((a0 + a1) + (a2 + a3));
        float act = fmaf(Aa, sigm(ms * s), Ba);

        const int ph = t & 1;
        g_s[ph][j] = act;
        __syncthreads();   // the single per-step barrier (gate exchange)

        float gi = g_s[ph][lane];
        float gf = g_s[ph][H   + lane];
        float gg = g_s[ph][2*H + lane];
        float go = g_s[ph][3*H + lane];
        c = fmaf(gf, c, gi * gg);
        h = go * tanh_s(c);

        p_cur    = p_next;
        tok_next = tok_next2;
    }

    __syncthreads();   // protect g_s[0] reuse below

    // backward LSTM: exactly one step (hs_b[0]) with zero initial state
    {
        int   tokL = xrow[T - 1];
        float gb   = Pb[tokL * G4 + j];
        g_s[0][j]  = fmaf(Aa, sigm(ms * gb), Ba);
    }
    if (gate == 0) hf_s[lane] = h;
    __syncthreads();

    if (j < H) {
        float i_ = g_s[0][j];
        float gg = g_s[0][2*H + j];
        float go = g_s[0][3*H + j];
        float cb = i_ * gg;               // f*c0 = 0
        hb_s[j] = go * tanh_s(cb);
    }
    __syncthreads();

    // final FC: y[b, j] = b_fc[j] + [h_f | h_b] . w_fc[j]
    if (j < 12) {
        float acc = b_fc[j];
        const float* wf = w_fc + j * (2 * H);
        #pragma unroll
        for (int k = 0; k < H; ++k) acc = fmaf(hf_s[k], wf[k], acc);
        #pragma unroll
        for (int k = 0; k < H; ++k) acc = fmaf(hb_s[k], wf[H + k], acc);
        out[b * 12 + j] = acc;
    }
}

extern "C" void kernel_launch(void* const* d_in, const int* in_sizes, int n_in,
                              void* d_out, int out_size, void* d_ws, size_t ws_size,
                              hipStream_t stream)
{
    const int*   x      = (const int*)  d_in[0];
    const float* emb    = (const float*)d_in[1];
    const float* w_ih_f = (const float*)d_in[2];
    const float* w_hh_f = (const float*)d_in[3];
    const float* b_ih_f = (const float*)d_in[4];
    const float* b_hh_f = (const float*)d_in[5];
    const float* w_ih_b = (const float*)d_in[6];
    // d_in[7] = w_hh_b (unused: backward runs exactly one step from zero state)
    const float* b_ih_b = (const float*)d_in[8];
    const float* b_hh_b = (const float*)d_in[9];
    const float* w_fc   = (const float*)d_in[10];
    const float* b_fc   = (const float*)d_in[11];
    float* out = (float*)d_out;

    const int B = out_size / 12;
    const int T = in_sizes[0] / B;
    const int V = in_sizes[1] / H;

    float* Pf = (float*)d_ws;                   // [V,4H]
    float* Pb = Pf + (size_t)V * G4;            // [V,4H]  (4 MB total)

    int pblocks = (V + 7) / 8;
    dim3 pgrid(pblocks, 2);
    proj_kernel<<<pgrid, 256, 0, stream>>>(emb, w_ih_f, b_ih_f, b_hh_f,
                                           w_ih_b, b_ih_b, b_hh_b, Pf, Pb, V);
    lstm_kernel<<<B, 256, 0, stream>>>(x, Pf, Pb, w_hh_f, w_fc, b_fc, out, T);
}